// Round 1
// 428.954 us; speedup vs baseline: 1.1563x; 1.1563x over previous
//
#include <hip/hip_runtime.h>
#include <math.h>

// Problem constants
#define NN 100000
#define DD 128
#define EE 600000
#define RR 5
#define MCNT (RR * NN)          // 500000 sort buckets (key = dst*5 + rel)
#define NB1 489                 // ceil(MCNT / 1024)

#define WSTR 136                // padded slot stride (f16) for transposed W
#define HALF_SLOTS 192
#define SLAB 32                 // rows per GEMM slab; 100000 = 3125*32
#define NSLAB (NN / SLAB)

// prep kernel partitions
#define CONV_BLKS 6250
#define ZERO_BLKS 245           // 245*2048 >= 500000
#define TW_BLKS  1216           // 1216*2 = 2432 weight slots

typedef _Float16 v8h __attribute__((ext_vector_type(8)));
typedef _Float16 h4  __attribute__((ext_vector_type(4)));
typedef float    v4f __attribute__((ext_vector_type(4)));

__device__ __forceinline__ float gelu_exact(float v) {
    return 0.5f * v * (1.0f + erff(v * 0.7071067811865476f));
}

// ---------------------------------------------------------------------------
// prep: fused convert_x (f32->f16) + cnt zero + weight transpose.
// New flat wt layout (slot-major, stride WSTR, wt[slot*WSTR + k]):
//   slots    0..383  : skip set (half-organized: s = half*192 + a*64 + c;
//                      a=0 lin_skip col, a=1 beta_s col, a=2 gamma_s col)
//   slots  384..1023 : lins_w  flat: slot = 384 + r*128 + col
//   slots 1024..2303 : films_w flat: slot = 1024 + r*256 + f (f=col of (D,2D))
//   slots 2304..2431 : linear1_w col
// ---------------------------------------------------------------------------
__global__ __launch_bounds__(256)
void prep(const float* __restrict__ x, _Float16* __restrict__ xh,
          int* __restrict__ cnt,
          const float* __restrict__ lin_skip_w,
          const float* __restrict__ film_skip_w,
          const float* __restrict__ lins_w,
          const float* __restrict__ films_w,
          const float* __restrict__ linear1_w,
          _Float16* __restrict__ wt)
{
    const int b = blockIdx.x;
    if (b < CONV_BLKS) {
        size_t u = (size_t)b * 256 + threadIdx.x;
        const float4 a = *(const float4*)(x + u * 8);
        const float4 c = *(const float4*)(x + u * 8 + 4);
        v8h o;
        o[0] = (_Float16)a.x; o[1] = (_Float16)a.y; o[2] = (_Float16)a.z; o[3] = (_Float16)a.w;
        o[4] = (_Float16)c.x; o[5] = (_Float16)c.y; o[6] = (_Float16)c.z; o[7] = (_Float16)c.w;
        *(v8h*)(xh + u * 8) = o;
    } else if (b < CONV_BLKS + ZERO_BLKS) {
        int i = (b - CONV_BLKS) * 2048 + threadIdx.x * 8;
        #pragma unroll
        for (int j = 0; j < 8; ++j)
            if (i + j < MCNT) cnt[i + j] = 0;
    } else {
        const int bb = (b - CONV_BLKS - ZERO_BLKS) * 2 + (threadIdx.x >> 7);
        const int k  = threadIdx.x & 127;
        float v;
        if (bb < 384) {
            const int half = bb / 192;
            const int rem  = bb % 192;
            const int a    = rem / 64;
            const int col  = half * 64 + (rem % 64);
            v = (a == 0) ? lin_skip_w[k * DD + col]
                         : film_skip_w[k * 2 * DD + (a - 1) * DD + col];
        } else if (bb < 1024) {
            const int r = (bb - 384) >> 7;
            const int c = (bb - 384) & 127;
            v = lins_w[((size_t)r * DD + k) * DD + c];
        } else if (bb < 2304) {
            const int r = (bb - 1024) >> 8;
            const int f = (bb - 1024) & 255;
            v = films_w[((size_t)r * DD + k) * 2 * DD + f];
        } else {
            v = linear1_w[k * DD + (bb - 2304)];
        }
        wt[(size_t)bb * WSTR + k] = (_Float16)v;
    }
}

// ---------------------------------------------------------------------------
// Counting sort of edges by key = dst*RR + rel  (dst-major!)
// ---------------------------------------------------------------------------
__global__ __launch_bounds__(256)
void count_kernel(const int* __restrict__ ei, const int* __restrict__ et,
                  int* __restrict__ cnt)
{
    int e = blockIdx.x * 256 + threadIdx.x;
    if (e < EE) atomicAdd(&cnt[(size_t)ei[EE + e] * RR + et[e]], 1);
}

__global__ __launch_bounds__(256)
void scan1(const int* __restrict__ cnt, int* __restrict__ partial,
           int* __restrict__ bsum)
{
    __shared__ int s[256];
    const int t = threadIdx.x;
    const int base = blockIdx.x * 1024 + t * 4;
    int v[4], sum = 0;
    #pragma unroll
    for (int j = 0; j < 4; ++j) {
        v[j] = (base + j < MCNT) ? cnt[base + j] : 0;
        sum += v[j];
    }
    s[t] = sum;
    __syncthreads();
    for (int off = 1; off < 256; off <<= 1) {
        int x = (t >= off) ? s[t - off] : 0;
        __syncthreads();
        s[t] += x;
        __syncthreads();
    }
    int run = s[t] - sum;
    if (t == 255) bsum[blockIdx.x] = s[255];
    #pragma unroll
    for (int j = 0; j < 4; ++j) {
        if (base + j < MCNT) partial[base + j] = run;
        run += v[j];
    }
}

__global__ __launch_bounds__(512)
void scan2(const int* __restrict__ bsum, int* __restrict__ bsum2)
{
    __shared__ int s[512];
    const int t = threadIdx.x;
    const int v = (t < NB1) ? bsum[t] : 0;
    s[t] = v;
    __syncthreads();
    for (int off = 1; off < 512; off <<= 1) {
        int x = (t >= off) ? s[t - off] : 0;
        __syncthreads();
        s[t] += x;
        __syncthreads();
    }
    if (t < NB1) bsum2[t] = s[t] - v;
}

__global__ __launch_bounds__(256)
void scan3(const int* __restrict__ partial, const int* __restrict__ bsum2,
           int* __restrict__ rowptr, int* __restrict__ head)
{
    const int t = threadIdx.x;
    const int base = blockIdx.x * 1024 + t * 4;
    const int add = bsum2[blockIdx.x];
    #pragma unroll
    for (int j = 0; j < 4; ++j) {
        if (base + j < MCNT) {
            int v = partial[base + j] + add;
            rowptr[base + j] = v;
            head[base + j]   = v;
        }
    }
    if (blockIdx.x == 0 && t == 0) rowptr[MCNT] = EE;
}

__global__ __launch_bounds__(256)
void scatter_kernel(const int* __restrict__ ei, const int* __restrict__ et,
                    int* __restrict__ head, int* __restrict__ srcs)
{
    int e = blockIdx.x * 256 + threadIdx.x;
    if (e < EE) {
        int pos = atomicAdd(&head[(size_t)ei[EE + e] * RR + et[e]], 1);
        srcs[pos] = ei[e];
    }
}

// ---------------------------------------------------------------------------
// Skip path: oa = relu(gamma_s * (x@lin_skip) + beta_s), f16 out. (unchanged)
// ---------------------------------------------------------------------------
__global__ __launch_bounds__(256)
void skip_mfma(const _Float16* __restrict__ xh,
               const _Float16* __restrict__ Wt,     // wt + 0 (skip set)
               _Float16* __restrict__ oa)
{
    __shared__ _Float16 Wl[HALF_SLOTS * WSTR];
    __shared__ _Float16 Al[SLAB * WSTR];
    const int tid  = threadIdx.x;
    const int wv   = tid >> 6;
    const int lane = tid & 63;
    const int l15  = lane & 15;
    const int quad = lane >> 4;

    for (int half = 0; half < 2; ++half) {
        __syncthreads();
        for (int u = tid; u < (HALF_SLOTS * WSTR) / 8; u += 256)
            *(v8h*)(Wl + (size_t)u * 8) =
                *(const v8h*)(Wt + (size_t)half * HALF_SLOTS * WSTR + (size_t)u * 8);

        const int c0 = half * 64 + wv * 16 + quad * 4;

        for (int s = blockIdx.x; s < NSLAB; s += gridDim.x) {
            __syncthreads();
            #pragma unroll
            for (int j = 0; j < 2; ++j) {
                int u = tid + j * 256;
                int row = u >> 4, c8 = u & 15;
                *(v8h*)(Al + row * WSTR + c8 * 8) =
                    *(const v8h*)(xh + ((size_t)s * SLAB + row) * DD + c8 * 8);
            }
            __syncthreads();

            v4f acc[3][2];
            #pragma unroll
            for (int a = 0; a < 3; ++a)
                #pragma unroll
                for (int rt = 0; rt < 2; ++rt)
                    acc[a][rt] = (v4f){0.f, 0.f, 0.f, 0.f};

            #pragma unroll
            for (int ks = 0; ks < 4; ++ks) {
                v8h xf0 = *(v8h*)(Al + l15 * WSTR + ks * 32 + quad * 8);
                v8h xf1 = *(v8h*)(Al + (16 + l15) * WSTR + ks * 32 + quad * 8);
                v8h wf[3];
                #pragma unroll
                for (int a = 0; a < 3; ++a)
                    wf[a] = *(v8h*)(Wl + (a * 64 + wv * 16 + l15) * WSTR + ks * 32 + quad * 8);
                #pragma unroll
                for (int a = 0; a < 3; ++a) {
                    acc[a][0] = __builtin_amdgcn_mfma_f32_16x16x32_f16(wf[a], xf0, acc[a][0], 0, 0, 0);
                    acc[a][1] = __builtin_amdgcn_mfma_f32_16x16x32_f16(wf[a], xf1, acc[a][1], 0, 0, 0);
                }
            }

            #pragma unroll
            for (int rt = 0; rt < 2; ++rt) {
                const size_t row = (size_t)s * SLAB + rt * 16 + l15;
                v4f xv = acc[0][rt], bv = acc[1][rt], gv = acc[2][rt];
                h4 o;
                o[0] = (_Float16)fmaxf(gv[0] * xv[0] + bv[0], 0.f);
                o[1] = (_Float16)fmaxf(gv[1] * xv[1] + bv[1], 0.f);
                o[2] = (_Float16)fmaxf(gv[2] * xv[2] + bv[2], 0.f);
                o[3] = (_Float16)fmaxf(gv[3] * xv[3] + bv[3], 0.f);
                *(h4*)(oa + row * DD + c0) = o;
            }
        }
    }
}

// ---------------------------------------------------------------------------
// lins_mfma: xl_r = x @ lins_w[r] for all 5 rels in one launch (f16 out).
// grid = 5*256; W_r (128 slots, 34.8 KB) LDS-stationary per block.
// ---------------------------------------------------------------------------
__global__ __launch_bounds__(256)
void lins_mfma(const _Float16* __restrict__ xh,
               const _Float16* __restrict__ Wt0,    // wt + 384*WSTR
               _Float16* __restrict__ xl)
{
    __shared__ _Float16 Wl[DD * WSTR];
    __shared__ _Float16 Al[SLAB * WSTR];
    const int r  = blockIdx.x >> 8;
    const int s0 = blockIdx.x & 255;
    const _Float16* Wt = Wt0 + (size_t)r * DD * WSTR;
    _Float16* xlr = xl + (size_t)r * NN * DD;
    const int tid  = threadIdx.x;
    const int wv   = tid >> 6;
    const int lane = tid & 63;
    const int l15  = lane & 15;
    const int quad = lane >> 4;

    for (int u = tid; u < (DD * WSTR) / 8; u += 256)
        *(v8h*)(Wl + (size_t)u * 8) = *(const v8h*)(Wt + (size_t)u * 8);

    for (int s = s0; s < NSLAB; s += 256) {
        __syncthreads();
        #pragma unroll
        for (int j = 0; j < 2; ++j) {
            int u = tid + j * 256;
            int row = u >> 4, c8 = u & 15;
            *(v8h*)(Al + row * WSTR + c8 * 8) =
                *(const v8h*)(xh + ((size_t)s * SLAB + row) * DD + c8 * 8);
        }
        __syncthreads();

        v4f acc[2][2];
        #pragma unroll
        for (int ct = 0; ct < 2; ++ct)
            #pragma unroll
            for (int rt = 0; rt < 2; ++rt)
                acc[ct][rt] = (v4f){0.f, 0.f, 0.f, 0.f};

        #pragma unroll
        for (int ks = 0; ks < 4; ++ks) {
            v8h xf0 = *(v8h*)(Al + l15 * WSTR + ks * 32 + quad * 8);
            v8h xf1 = *(v8h*)(Al + (16 + l15) * WSTR + ks * 32 + quad * 8);
            #pragma unroll
            for (int ct = 0; ct < 2; ++ct) {
                v8h wf = *(v8h*)(Wl + (wv * 32 + ct * 16 + l15) * WSTR + ks * 32 + quad * 8);
                acc[ct][0] = __builtin_amdgcn_mfma_f32_16x16x32_f16(wf, xf0, acc[ct][0], 0, 0, 0);
                acc[ct][1] = __builtin_amdgcn_mfma_f32_16x16x32_f16(wf, xf1, acc[ct][1], 0, 0, 0);
            }
        }

        #pragma unroll
        for (int ct = 0; ct < 2; ++ct)
            #pragma unroll
            for (int rt = 0; rt < 2; ++rt) {
                const size_t row = (size_t)s * SLAB + rt * 16 + l15;
                const int c0 = wv * 32 + ct * 16 + quad * 4;
                h4 o;
                o[0] = (_Float16)acc[ct][rt][0];
                o[1] = (_Float16)acc[ct][rt][1];
                o[2] = (_Float16)acc[ct][rt][2];
                o[3] = (_Float16)acc[ct][rt][3];
                *(h4*)(xlr + row * DD + c0) = o;
            }
    }
}

// ---------------------------------------------------------------------------
// agg_all: one block per 32-dst chunk. Per relation:
//   (1) beta/gamma = x[chunk] @ films_w[r] + films_b[r] via MFMA
//       (W streamed from L2 per-lane; result transposed through LDS BG tile)
//   (2) gather/relu/mean over the (dst,rel) segment of the dst-major sort.
// Accumulates all 5 relation means in fp32 registers; single oa RMW at end.
// ---------------------------------------------------------------------------
__global__ __launch_bounds__(256)
void agg_all(const int* __restrict__ rowptr,
             const int* __restrict__ srcs,
             const _Float16* __restrict__ xh,
             const _Float16* __restrict__ wfilm,    // wt + 1024*WSTR
             const float* __restrict__ fb,          // films_b
             const _Float16* __restrict__ xl,       // 5 contiguous buffers
             _Float16* __restrict__ oa)
{
    __shared__ _Float16 Al[SLAB * WSTR];            // chunk x rows (8.7 KB)
    __shared__ _Float16 BG[SLAB][264];              // beta|gamma, +8 pad (16.9 KB)
    __shared__ int RP[SLAB * RR + 1];               // rowptr slice (644 B)

    const int tid  = threadIdx.x;
    const int wv   = tid >> 6;
    const int lane = tid & 63;
    const int l15  = lane & 15;
    const int quad = lane >> 4;
    const int g    = tid >> 4;                      // 16 groups of 16 lanes
    const int gl   = tid & 15;
    const int d0   = blockIdx.x * SLAB;

    #pragma unroll
    for (int j = 0; j < 2; ++j) {
        int u = tid + j * 256;
        int row = u >> 4, c8 = u & 15;
        *(v8h*)(Al + row * WSTR + c8 * 8) =
            *(const v8h*)(xh + ((size_t)(d0 + row)) * DD + c8 * 8);
    }
    if (tid <= SLAB * RR) RP[tid] = rowptr[d0 * RR + tid];

    float accT[2][8];
    #pragma unroll
    for (int sub = 0; sub < 2; ++sub)
        #pragma unroll
        for (int q = 0; q < 8; ++q) accT[sub][q] = 0.f;

    for (int r = 0; r < RR; ++r) {
        __syncthreads();    // Al/RP ready (r=0); BG free of prior-rel readers

        // --- GEMM: BG[32][256] = Al @ films_w[r] + bias ---
        v4f acc[4][2];
        #pragma unroll
        for (int tt = 0; tt < 4; ++tt) {
            acc[tt][0] = (v4f){0.f, 0.f, 0.f, 0.f};
            acc[tt][1] = (v4f){0.f, 0.f, 0.f, 0.f};
        }
        #pragma unroll
        for (int ks = 0; ks < 4; ++ks) {
            v8h xf0 = *(v8h*)(Al + l15 * WSTR + ks * 32 + quad * 8);
            v8h xf1 = *(v8h*)(Al + (16 + l15) * WSTR + ks * 32 + quad * 8);
            #pragma unroll
            for (int tt = 0; tt < 4; ++tt) {
                const int t = wv * 4 + tt;
                v8h wf = *(const v8h*)(wfilm +
                    ((size_t)r * 256 + t * 16 + l15) * WSTR + ks * 32 + quad * 8);
                acc[tt][0] = __builtin_amdgcn_mfma_f32_16x16x32_f16(wf, xf0, acc[tt][0], 0, 0, 0);
                acc[tt][1] = __builtin_amdgcn_mfma_f32_16x16x32_f16(wf, xf1, acc[tt][1], 0, 0, 0);
            }
        }
        #pragma unroll
        for (int tt = 0; tt < 4; ++tt) {
            const int t  = wv * 4 + tt;
            const int f0 = t * 16 + quad * 4;
            const float4 bia = *(const float4*)(fb + r * 2 * DD + f0);
            #pragma unroll
            for (int rt = 0; rt < 2; ++rt) {
                h4 o;
                o[0] = (_Float16)(acc[tt][rt][0] + bia.x);
                o[1] = (_Float16)(acc[tt][rt][1] + bia.y);
                o[2] = (_Float16)(acc[tt][rt][2] + bia.z);
                o[3] = (_Float16)(acc[tt][rt][3] + bia.w);
                *(h4*)(&BG[rt * 16 + l15][f0]) = o;
            }
        }
        __syncthreads();

        // --- gather/relu/mean for this relation ---
        const _Float16* xlr = xl + (size_t)r * NN * DD;
        #pragma unroll
        for (int sub = 0; sub < 2; ++sub) {
            const int dl = g * 2 + sub;
            const int p0 = RP[dl * RR + r];
            const int p1 = RP[dl * RR + r + 1];
            const int k  = p1 - p0;
            if (k <= 0) continue;
            const v8h bs = *(const v8h*)(&BG[dl][gl * 8]);
            const v8h gs = *(const v8h*)(&BG[dl][DD + gl * 8]);
            float a2[8];
            #pragma unroll
            for (int q = 0; q < 8; ++q) a2[q] = 0.f;
            int p = p0;
            while (p < p1) {
                const int kb = min(p1 - p, 4);
                int sidx[4];
                #pragma unroll
                for (int j = 0; j < 4; ++j)
                    sidx[j] = srcs[p + min(j, kb - 1)];   // clamped: valid
                v8h xv[4];
                #pragma unroll
                for (int j = 0; j < 4; ++j)
                    xv[j] = *(const v8h*)(xlr + (size_t)sidx[j] * DD + gl * 8);
                #pragma unroll
                for (int j = 0; j < 4; ++j) {
                    if (j < kb) {
                        #pragma unroll
                        for (int q = 0; q < 8; ++q)
                            a2[q] += fmaxf((float)gs[q] * (float)xv[j][q] + (float)bs[q], 0.f);
                    }
                }
                p += kb;
            }
            const float inv = 1.0f / (float)k;
            #pragma unroll
            for (int q = 0; q < 8; ++q) accT[sub][q] += a2[q] * inv;
        }
    }

    // --- single oa RMW (skip value + sum of relation means) ---
    #pragma unroll
    for (int sub = 0; sub < 2; ++sub) {
        const int d = d0 + g * 2 + sub;
        _Float16* dp = oa + (size_t)d * DD + gl * 8;
        v8h old = *(v8h*)dp, nw;
        #pragma unroll
        for (int q = 0; q < 8; ++q)
            nw[q] = (_Float16)((float)old[q] + accT[sub][q]);
        *(v8h*)dp = nw;
    }
}

// ---------------------------------------------------------------------------
// out = gelu(oa) @ linear1_w + linear1_b   (f16 in, fp32 out) (unchanged)
// ---------------------------------------------------------------------------
__global__ __launch_bounds__(256)
void final_mfma(const _Float16* __restrict__ oa,
                const _Float16* __restrict__ Wt,    // wt + 2304*WSTR
                const float* __restrict__ bias,
                float* __restrict__ out)
{
    __shared__ _Float16 Wl[DD * WSTR];
    __shared__ _Float16 Al[SLAB * WSTR];
    const int tid  = threadIdx.x;
    const int wv   = tid >> 6;
    const int lane = tid & 63;
    const int l15  = lane & 15;
    const int quad = lane >> 4;

    for (int u = tid; u < (DD * WSTR) / 8; u += 256)
        *(v8h*)(Wl + (size_t)u * 8) = *(const v8h*)(Wt + (size_t)u * 8);

    float4 bf[2];
    #pragma unroll
    for (int ct = 0; ct < 2; ++ct)
        bf[ct] = *(const float4*)(bias + wv * 32 + ct * 16 + quad * 4);

    for (int s = blockIdx.x; s < NSLAB; s += gridDim.x) {
        __syncthreads();
        #pragma unroll
        for (int j = 0; j < 2; ++j) {
            int u = tid + j * 256;
            int row = u >> 4, c8 = (u & 15) * 8;
            v8h g = *(const v8h*)(oa + ((size_t)s * SLAB + row) * DD + c8);
            v8h o;
            #pragma unroll
            for (int q = 0; q < 8; ++q)
                o[q] = (_Float16)gelu_exact((float)g[q]);
            *(v8h*)(Al + row * WSTR + c8) = o;
        }
        __syncthreads();

        v4f acc[2][2];
        #pragma unroll
        for (int ct = 0; ct < 2; ++ct)
            #pragma unroll
            for (int rt = 0; rt < 2; ++rt)
                acc[ct][rt] = (v4f){0.f, 0.f, 0.f, 0.f};

        #pragma unroll
        for (int ks = 0; ks < 4; ++ks) {
            v8h xf0 = *(v8h*)(Al + l15 * WSTR + ks * 32 + quad * 8);
            v8h xf1 = *(v8h*)(Al + (16 + l15) * WSTR + ks * 32 + quad * 8);
            v8h wf[2];
            #pragma unroll
            for (int ct = 0; ct < 2; ++ct)
                wf[ct] = *(v8h*)(Wl + (wv * 32 + ct * 16 + l15) * WSTR + ks * 32 + quad * 8);
            #pragma unroll
            for (int ct = 0; ct < 2; ++ct) {
                acc[ct][0] = __builtin_amdgcn_mfma_f32_16x16x32_f16(wf[ct], xf0, acc[ct][0], 0, 0, 0);
                acc[ct][1] = __builtin_amdgcn_mfma_f32_16x16x32_f16(wf[ct], xf1, acc[ct][1], 0, 0, 0);
            }
        }

        #pragma unroll
        for (int ct = 0; ct < 2; ++ct)
            #pragma unroll
            for (int rt = 0; rt < 2; ++rt) {
                const size_t row = (size_t)s * SLAB + rt * 16 + l15;
                const int c0 = wv * 32 + ct * 16 + quad * 4;
                float4 o;
                o.x = acc[ct][rt][0] + bf[ct].x;
                o.y = acc[ct][rt][1] + bf[ct].y;
                o.z = acc[ct][rt][2] + bf[ct].z;
                o.w = acc[ct][rt][3] + bf[ct].w;
                *(float4*)(out + row * DD + c0) = o;
            }
    }
}

extern "C" void kernel_launch(void* const* d_in, const int* in_sizes, int n_in,
                              void* d_out, int out_size, void* d_ws, size_t ws_size,
                              hipStream_t stream)
{
    const float* x           = (const float*)d_in[0];
    const int*   ei          = (const int*)d_in[1];
    const int*   et          = (const int*)d_in[2];
    const float* lin_skip_w  = (const float*)d_in[3];
    const float* film_skip_w = (const float*)d_in[4];
    const float* lins_w      = (const float*)d_in[5];
    const float* films_w     = (const float*)d_in[6];
    const float* films_b     = (const float*)d_in[7];
    const float* linear1_w   = (const float*)d_in[8];
    const float* linear1_b   = (const float*)d_in[9];
    float* out = (float*)d_out;
    char*  ws  = (char*)d_ws;

    // workspace layout (bytes, f16 regions 256-aligned) — ~190.3 MB total
    _Float16* xh      = (_Float16*)(ws);                   // 25,600,000
    _Float16* wt      = (_Float16*)(ws + 25600000);        //    661,504
    _Float16* xl      = (_Float16*)(ws + 26261504);        // 5 x 25,600,000
    _Float16* oa      = (_Float16*)(ws + 154261504);       // 25,600,000
    int*      cnt     = (int*)     (ws + 179861504);       //  2,000,000
    int*      partial = (int*)     (ws + 181861504);       //  2,000,000
    int*      rowptr  = (int*)     (ws + 183861504);       //  2,000,128
    int*      head    = (int*)     (ws + 185861632);       //  2,000,000
    int*      srcs    = (int*)     (ws + 187861632);       //  2,400,000
    int*      bsum    = (int*)     (ws + 190261632);       //      4,096
    int*      bsum2   = (int*)     (ws + 190265728);       //      4,096

    prep<<<CONV_BLKS + ZERO_BLKS + TW_BLKS, 256, 0, stream>>>(
        x, xh, cnt, lin_skip_w, film_skip_w, lins_w, films_w, linear1_w, wt);

    // counting sort of edges by (dst, rel)
    count_kernel<<<(EE + 255) / 256, 256, 0, stream>>>(ei, et, cnt);
    scan1<<<NB1, 256, 0, stream>>>(cnt, partial, bsum);
    scan2<<<1, 512, 0, stream>>>(bsum, bsum2);
    scan3<<<NB1, 256, 0, stream>>>(partial, bsum2, rowptr, head);
    scatter_kernel<<<(EE + 255) / 256, 256, 0, stream>>>(ei, et, head, srcs);

    // skip path -> oa (f16)
    skip_mfma<<<512, 256, 0, stream>>>(xh, wt, oa);

    // xl_r for all 5 relations (one launch)
    lins_mfma<<<1280, 256, 0, stream>>>(xh, wt + (size_t)384 * WSTR, xl);

    // fused: per-chunk beta/gamma GEMM + gather/mean over all relations
    agg_all<<<NSLAB, 256, 0, stream>>>(rowptr, srcs, xh,
                                       wt + (size_t)1024 * WSTR,
                                       films_b, xl, oa);

    final_mfma<<<512, 256, 0, stream>>>(oa, wt + (size_t)2304 * WSTR,
                                        linear1_b, out);
}